// Round 2
// baseline (173.161 us; speedup 1.0000x reference)
//
#include <hip/hip_runtime.h>

// S4D diagonal complex SSM scan, 2 batches per wave.
//   s_n[l] = w_n * s_n[l-1] + x[l];  y[l] = 2*Re sum_n Ceff_n * s_n[l]
//
// Mapping: one wave per (b-pair, h); lane n owns state n for both batches
// (batches share h => identical w, Ceff). Two independent dependency chains
// interleave per lane => ~2x issue density vs 1 seq/wave. x broadcast via
// v_readlane (literal lane, VALU) instead of __shfl/ds_bpermute. Next x
// chunk software-prefetched. Per 64-step chunk: contributions -> LDS
// [t*65+n] (stride 65 => <=2 lanes/bank, free), then lane j reduces row j.

#define BATCH_ 8
#define H_ 256
#define N_ 64
#define L_ 2048

__device__ __forceinline__ float bcast(float v, int lane) {
    return __int_as_float(__builtin_amdgcn_readlane(__float_as_int(v), lane));
}

__global__ __launch_bounds__(64) void s4d_scan_kernel(
    const float* __restrict__ x,       // (B, H, L)
    const float* __restrict__ A_real,  // (H, N)
    const float* __restrict__ A_imag,  // (H, N)
    const float* __restrict__ Bmat,    // (1, H, N, 2)
    const float* __restrict__ Cmat,    // (1, H, N, 2)
    const float* __restrict__ inv_dt,  // (H, 1)
    float* __restrict__ out)           // (B, 1, H, L)
{
    __shared__ float lds0[64 * 65];
    __shared__ float lds1[64 * 65];

    const int h  = blockIdx.x & (H_ - 1);
    const int b2 = blockIdx.x >> 8;    // 0..3 -> batches b2 and b2+4
    const int n  = threadIdx.x;        // 0..63 : state index

    // ---- per-(h,n) parameter setup (shared by both batches) ----
    const int hn = h * N_ + n;
    const float ar = A_real[hn];
    const float ai = A_imag[hn];
    const float Ar = -expf(ar);        // A = -exp(A_real) - i*A_imag
    const float Ai = -ai;
    const float dtv = expf(inv_dt[h]);
    const float dr = dtv * Ar;
    const float di = dtv * Ai;
    const float ew = expf(dr);         // w = exp(dtA)
    float sdi, cdi;
    sincosf(di, &sdi, &cdi);
    const float wr = ew * cdi;
    const float wi = ew * sdi;
    const float em1r = wr - 1.0f;      // t = (exp(dtA)-1)/A
    const float em1i = wi;
    const float invden = 1.0f / (Ar * Ar + Ai * Ai);
    const float tr = (em1r * Ar + em1i * Ai) * invden;
    const float ti = (em1i * Ar - em1r * Ai) * invden;
    const float br = Bmat[2 * hn], bi = Bmat[2 * hn + 1];
    const float cr = Cmat[2 * hn], ci = Cmat[2 * hn + 1];
    const float bcr = br * cr - bi * ci;
    const float bci = br * ci + bi * cr;
    const float Cr = 2.0f * (bcr * tr - bci * ti);  // Ceff (x2 folded in)
    const float Ci = 2.0f * (bcr * ti + bci * tr);

    const float* xp0 = x + ((size_t)b2 * H_ + h) * L_;
    const float* xp1 = x + ((size_t)(b2 + 4) * H_ + h) * L_;
    float*       yp0 = out + ((size_t)b2 * H_ + h) * L_;
    float*       yp1 = out + ((size_t)(b2 + 4) * H_ + h) * L_;

    float s0r = 0.f, s0i = 0.f, s1r = 0.f, s1i = 0.f;

    // prefetch chunk 0
    float xc0 = xp0[n];
    float xc1 = xp1[n];

    for (int l0 = 0; l0 < L_; l0 += 64) {
        // software-prefetch next chunk (hidden behind 64 steps of compute)
        float xn0 = 0.f, xn1 = 0.f;
        if (l0 + 64 < L_) {
            xn0 = xp0[l0 + 64 + n];
            xn1 = xp1[l0 + 64 + n];
        }

        #pragma unroll
        for (int t = 0; t < 64; ++t) {
            const float xt0 = bcast(xc0, t);
            const float xt1 = bcast(xc1, t);
            // batch 0 chain
            const float a0  = fmaf(s0i, -wi, xt0);
            const float n0r = fmaf(s0r, wr, a0);
            const float n0i = fmaf(s0r, wi, s0i * wr);
            s0r = n0r; s0i = n0i;
            lds0[t * 65 + n] = fmaf(Cr, s0r, -(Ci * s0i));
            // batch 1 chain (independent)
            const float a1  = fmaf(s1i, -wi, xt1);
            const float n1r = fmaf(s1r, wr, a1);
            const float n1i = fmaf(s1r, wi, s1i * wr);
            s1r = n1r; s1i = n1i;
            lds1[t * 65 + n] = fmaf(Cr, s1r, -(Ci * s1i));
        }
        __syncthreads();

        // lane j reduces row j of both buffers
        const float* r0 = &lds0[n * 65];
        const float* r1 = &lds1[n * 65];
        float a00 = 0.f, a01 = 0.f, a02 = 0.f, a03 = 0.f;
        float a10 = 0.f, a11 = 0.f, a12 = 0.f, a13 = 0.f;
        #pragma unroll
        for (int m = 0; m < 64; m += 4) {
            a00 += r0[m + 0]; a01 += r0[m + 1];
            a02 += r0[m + 2]; a03 += r0[m + 3];
            a10 += r1[m + 0]; a11 += r1[m + 1];
            a12 += r1[m + 2]; a13 += r1[m + 3];
        }
        const float y0 = (a00 + a01) + (a02 + a03);
        const float y1 = (a10 + a11) + (a12 + a13);
        yp0[l0 + n] = fmaxf(y0, 0.0f);
        yp1[l0 + n] = fmaxf(y1, 0.0f);
        __syncthreads();

        xc0 = xn0;
        xc1 = xn1;
    }
}

extern "C" void kernel_launch(void* const* d_in, const int* in_sizes, int n_in,
                              void* d_out, int out_size, void* d_ws, size_t ws_size,
                              hipStream_t stream) {
    const float* x      = (const float*)d_in[0];
    const float* A_real = (const float*)d_in[1];
    const float* A_imag = (const float*)d_in[2];
    const float* Bmat   = (const float*)d_in[3];
    const float* Cmat   = (const float*)d_in[4];
    const float* inv_dt = (const float*)d_in[5];
    float* out = (float*)d_out;

    dim3 grid((BATCH_ / 2) * H_);   // 1024 waves: (b2, h)
    dim3 block(64);
    s4d_scan_kernel<<<grid, block, 0, stream>>>(x, A_real, A_imag, Bmat, Cmat,
                                                inv_dt, out);
}

// Round 3
// 165.375 us; speedup vs baseline: 1.0471x; 1.0471x over previous
//
#include <hip/hip_runtime.h>

// S4D diagonal complex SSM, summary-first 2-kernel chunked scan.
//
// Recurrence: s[l] = w*s[l-1] + x[l];  y[l] = relu(2*Re sum_n Ceff_n*s_n[l])
// In u-space (u = 2*Ceff*s): u[l] = w*u[l-1] + 2*Ceff*x[l]; contrib = Re(u).
//
// K1 (summaries): per (seq, chunk of 256): zero-init s-space scan, no
//   output, final state -> ws.  5 instr/step, no LDS -> high occupancy.
// K2 (main): per (seq, chunk of 512): true initial state = combine prior
//   summaries with P = w^256; then full u-space scan (8 instr/step) with
//   32-step LDS transpose-reduce (stride 68: conflict-free writes, aligned
//   b128 reads, only 8.7 KB/wave -> ~19 waves/CU vs 4 before).

#define BATCH_ 8
#define H_ 256
#define N_ 64
#define L_ 2048
#define SEQ_ (BATCH_ * H_)

#define C1_ 8
#define Q1_ 256
#define C2_ 4
#define Q2_ 512
#define STRIDE_ 68   // LDS row stride (words): writes 2-way (free), b128 reads bank-uniform

__device__ __forceinline__ float bcast(float v, int lane) {
    return __int_as_float(__builtin_amdgcn_readlane(__float_as_int(v), lane));
}

// compute w = exp(dt*A) for (h, n); optionally Ceff2 = 2*B*C*(w-1)/A
__device__ __forceinline__ void s4d_params(
    const float* __restrict__ A_real, const float* __restrict__ A_imag,
    const float* __restrict__ Bmat, const float* __restrict__ Cmat,
    const float* __restrict__ inv_dt, int h, int n, bool want_c,
    float& wr, float& wi, float& dr, float& di, float& Cr, float& Ci)
{
    const int hn = h * N_ + n;
    const float Ar = -expf(A_real[hn]);   // A = -exp(A_real) - i*A_imag
    const float Ai = -A_imag[hn];
    const float dtv = expf(inv_dt[h]);
    dr = dtv * Ar;
    di = dtv * Ai;
    const float ew = expf(dr);
    float sdi, cdi;
    sincosf(di, &sdi, &cdi);
    wr = ew * cdi;
    wi = ew * sdi;
    if (want_c) {
        const float em1r = wr - 1.0f;     // (w-1)/A
        const float em1i = wi;
        const float invden = 1.0f / (Ar * Ar + Ai * Ai);
        const float tr = (em1r * Ar + em1i * Ai) * invden;
        const float ti = (em1i * Ar - em1r * Ai) * invden;
        const float br = Bmat[2 * hn], bi = Bmat[2 * hn + 1];
        const float cr = Cmat[2 * hn], ci = Cmat[2 * hn + 1];
        const float bcr = br * cr - bi * ci;
        const float bci = br * ci + bi * cr;
        Cr = 2.0f * (bcr * tr - bci * ti);
        Ci = 2.0f * (bcr * ti + bci * tr);
    }
}

// ---------------- K1: per-chunk state summaries ----------------
__global__ __launch_bounds__(64) void s4d_sum_kernel(
    const float* __restrict__ x,
    const float* __restrict__ A_real, const float* __restrict__ A_imag,
    const float* __restrict__ inv_dt,
    float2* __restrict__ V)            // (SEQ, C1, 64) complex
{
    const int bid = blockIdx.x;        // seq*C1 + c
    const int c   = bid & (C1_ - 1);
    const int seq = bid >> 3;
    const int h   = seq & (H_ - 1);
    const int n   = threadIdx.x;

    float wr, wi, dr, di, Cr, Ci;
    s4d_params(A_real, A_imag, nullptr, nullptr, inv_dt, h, n, false,
               wr, wi, dr, di, Cr, Ci);

    const float* xp = x + (size_t)seq * L_ + c * Q1_;
    float vr = 0.0f, vi = 0.0f;
    float xv = xp[n];

    for (int l0 = 0; l0 < Q1_; l0 += 64) {
        float xnx = 0.0f;
        if (l0 + 64 < Q1_) xnx = xp[l0 + 64 + n];
        #pragma unroll
        for (int t = 0; t < 64; ++t) {
            const float xt = bcast(xv, t);
            const float nvr = fmaf(wr, vr, fmaf(-wi, vi, xt));
            const float nvi = fmaf(wi, vr, vi * wr);
            vr = nvr; vi = nvi;
        }
        xv = xnx;
    }
    V[(size_t)bid * 64 + n] = make_float2(vr, vi);
}

// ---------------- K2: full scan from true initial state ----------------
__global__ __launch_bounds__(64) void s4d_scan_kernel(
    const float* __restrict__ x,
    const float* __restrict__ A_real, const float* __restrict__ A_imag,
    const float* __restrict__ Bmat, const float* __restrict__ Cmat,
    const float* __restrict__ inv_dt,
    const float2* __restrict__ V,
    float* __restrict__ out)
{
    __shared__ float lds[32 * STRIDE_];

    const int bid = blockIdx.x;        // seq*C2 + c
    const int c   = bid & (C2_ - 1);
    const int seq = bid >> 2;
    const int h   = seq & (H_ - 1);
    const int n   = threadIdx.x;

    float wr, wi, dr, di, Cr, Ci;
    s4d_params(A_real, A_imag, Bmat, Cmat, inv_dt, h, n, true,
               wr, wi, dr, di, Cr, Ci);

    // P = w^Q1 (direct)
    const float eP = expf((float)Q1_ * dr);
    float sP, cP;
    sincosf((float)Q1_ * di, &sP, &cP);
    const float Pr = eP * cP;
    const float Pi = eP * sP;

    // combine prior summaries: s_init = sum_j P^(jmax-1-j) * V[j]
    float sr = 0.0f, si = 0.0f;
    const int jmax = c * (C1_ / C2_);  // 2c K1-chunks precede this K2-chunk
    for (int j = 0; j < jmax; ++j) {
        const float2 v = V[((size_t)seq * C1_ + j) * 64 + n];
        const float nr = fmaf(Pr, sr, fmaf(-Pi, si, v.x));
        const float ni = fmaf(Pi, sr, fmaf(Pr, si, v.y));
        sr = nr; si = ni;
    }
    // u = Ceff2 * s_init
    float ur = Cr * sr - Ci * si;
    float ui = Cr * si + Ci * sr;

    const float* xp = x   + (size_t)seq * L_ + c * Q2_;
    float*       yp = out + (size_t)seq * L_ + c * Q2_;

    const int row  = n & 31;
    const int half = n >> 5;
    const float4* rdp = (const float4*)&lds[row * STRIDE_ + half * 32];
    const bool storer = (n < 32);

    float xv = xp[n];

    for (int l0 = 0; l0 < Q2_; l0 += 64) {
        float xnx = 0.0f;
        if (l0 + 64 < Q2_) xnx = xp[l0 + 64 + n];

        #pragma unroll
        for (int sub = 0; sub < 2; ++sub) {
            #pragma unroll
            for (int t = 0; t < 32; ++t) {
                const float xt = bcast(xv, sub * 32 + t);
                const float qr = Cr * xt;
                const float qi = Ci * xt;
                const float nur = fmaf(wr, ur, fmaf(-wi, ui, qr));
                const float nui = fmaf(wi, ur, fmaf(wr, ui, qi));
                ur = nur; ui = nui;
                lds[t * STRIDE_ + n] = ur;   // contribution = Re(u)
            }
            __syncthreads();

            // lane j sums half of row (j&31): 8 aligned b128 reads
            float4 acc = rdp[0];
            #pragma unroll
            for (int m = 1; m < 8; ++m) {
                const float4 v4 = rdp[m];
                acc.x += v4.x; acc.y += v4.y; acc.z += v4.z; acc.w += v4.w;
            }
            float p = (acc.x + acc.y) + (acc.z + acc.w);
            p += __shfl_xor(p, 32);
            if (storer) yp[l0 + sub * 32 + row] = fmaxf(p, 0.0f);
            __syncthreads();
        }
        xv = xnx;
    }
}

extern "C" void kernel_launch(void* const* d_in, const int* in_sizes, int n_in,
                              void* d_out, int out_size, void* d_ws, size_t ws_size,
                              hipStream_t stream) {
    const float* x      = (const float*)d_in[0];
    const float* A_real = (const float*)d_in[1];
    const float* A_imag = (const float*)d_in[2];
    const float* Bmat   = (const float*)d_in[3];
    const float* Cmat   = (const float*)d_in[4];
    const float* inv_dt = (const float*)d_in[5];
    float* out = (float*)d_out;
    float2* V  = (float2*)d_ws;        // SEQ*C1*64 complex = 8.4 MB

    s4d_sum_kernel<<<dim3(SEQ_ * C1_), dim3(64), 0, stream>>>(
        x, A_real, A_imag, inv_dt, V);
    s4d_scan_kernel<<<dim3(SEQ_ * C2_), dim3(64), 0, stream>>>(
        x, A_real, A_imag, Bmat, Cmat, inv_dt, V, out);
}

// Round 4
// 118.973 us; speedup vs baseline: 1.4555x; 1.3900x over previous
//
#include <hip/hip_runtime.h>

// S4D via chunked MFMA reformulation (Q=64 chunks, 32 chunks/seq).
//
//  y[c*64+t] = sum_j k[t-j]*x[c*64+j]              (lower-tri Toeplitz, local)
//            + Re( sum_n Ceff2_n w_n^{t+1} S_n[c] ) (carry from prior chunks)
//  S_n[c]    = w^64 * S_n[c-1] + V_n[c-1],  V_n[c] = sum_j w_n^{63-j} x[c*64+j]
//
//  prep  : per h, build bf16 matrices  W1s[n][j]=w^(63-j), TLs[t][j]=k[t-j],
//          W2sr[t][n]=Re(Ceff2*w^(t+1)), W2si[t][n]=-Im(...), E=w^64
//  phaseA: MFMA GEMM  V[(b,c)][n] = X[(b,c)][j] * W1s^T   (per h)
//  phaseB: tiny scan of summaries -> S (state entering each chunk), in-place
//  phaseC: MFMA GEMM  y[(b,c)][t] = Xhi*TL + Xlo*TL + Sr*W2r + Si*W2i, relu
//
//  All GEMMs transposed (D rows=(b,c), cols=n/t) so stores are line-coalesced.
//  Layouts (verified gfx950): A: A[m=l&15][k=(l>>4)*8+j]; B: B[k=(l>>4)*8+j][n=l&15];
//  D: D[(l>>4)*4+r][l&15].

#define B_ 8
#define H_ 256
#define N_ 64
#define L_ 2048
#define Q_ 64
#define NC_ 32          // chunks per sequence
#define COLS_ 256       // (b,c) columns per h

typedef __attribute__((ext_vector_type(8))) short bf16x8;
typedef __attribute__((ext_vector_type(4))) float f32x4;

// ---- ws layout (bytes) ----
#define WS_V    0                      // ushort2 V/S: 256h * 256col * 64n * 4B = 16 MiB
#define WS_W1R  (16777216)             // ushort, 256h*4096*2B = 2 MiB each
#define WS_W1I  (WS_W1R + 2097152)
#define WS_TL   (WS_W1I + 2097152)
#define WS_W2R  (WS_TL  + 2097152)
#define WS_W2I  (WS_W2R + 2097152)
#define WS_E    (WS_W2I + 2097152)     // float2, 256h*64n*8B = 128 KiB

__device__ __forceinline__ unsigned short bf16_rne(float f) {
    unsigned int u = __float_as_uint(f);
    u += 0x7FFF + ((u >> 16) & 1);
    return (unsigned short)(u >> 16);
}
__device__ __forceinline__ float bf16_to_f(unsigned short h) {
    return __uint_as_float(((unsigned int)h) << 16);
}

// ================= prep: per-h parameter matrices =================
__global__ __launch_bounds__(64) void s4d_prep(
    const float* __restrict__ A_real, const float* __restrict__ A_imag,
    const float* __restrict__ Bmat, const float* __restrict__ Cmat,
    const float* __restrict__ inv_dt,
    unsigned short* __restrict__ W1sr, unsigned short* __restrict__ W1si,
    unsigned short* __restrict__ TLs,
    unsigned short* __restrict__ W2sr, unsigned short* __restrict__ W2si,
    float2* __restrict__ Earr)
{
    __shared__ float lds[64 * 68];
    __shared__ float klds[64];

    const int h = blockIdx.x;
    const int n = threadIdx.x;
    const int hn = h * N_ + n;

    const float Ar = -expf(A_real[hn]);     // A = -exp(A_real) - i*A_imag
    const float Ai = -A_imag[hn];
    const float dtv = expf(inv_dt[h]);
    const float dr = dtv * Ar;
    const float di = dtv * Ai;
    const float ew = expf(dr);
    float sdi, cdi;
    sincosf(di, &sdi, &cdi);
    const float wr = ew * cdi;              // w = exp(dt*A)
    const float wi = ew * sdi;
    const float em1r = wr - 1.0f;           // (w-1)/A
    const float em1i = wi;
    const float invden = 1.0f / (Ar * Ar + Ai * Ai);
    const float tr = (em1r * Ar + em1i * Ai) * invden;
    const float ti = (em1i * Ar - em1r * Ai) * invden;
    const float br = Bmat[2 * hn], bi = Bmat[2 * hn + 1];
    const float cr = Cmat[2 * hn], ci = Cmat[2 * hn + 1];
    const float bcr = br * cr - bi * ci;
    const float bci = br * ci + bi * cr;
    const float Cr = 2.0f * (bcr * tr - bci * ti);   // Ceff2 = 2*B*C*(w-1)/A
    const float Ci = 2.0f * (bcr * ti + bci * tr);

    // E = w^64
    const float e64 = expf(64.0f * dr);
    float s64, c64;
    sincosf(64.0f * di, &s64, &c64);
    Earr[h * N_ + n] = make_float2(e64 * c64, e64 * s64);

    unsigned short* w1r = W1sr + h * 4096;
    unsigned short* w1i = W1si + h * 4096;
    unsigned short* w2r = W2sr + h * 4096;
    unsigned short* w2i = W2si + h * 4096;

    float pr = 1.0f, pi = 0.0f;             // w^m
    for (int m = 0; m <= 64; ++m) {
        const float qr = Cr * pr - Ci * pi; // Re(Ceff2 * w^m)
        const float qi = Cr * pi + Ci * pr;
        if (m < 64) {
            lds[m * 68 + n] = qr;           // contribution to k[m]
            w1r[n * 64 + (63 - m)] = bf16_rne(pr);   // W1s[n][j]=w^(63-j)
            w1i[n * 64 + (63 - m)] = bf16_rne(pi);
        }
        if (m >= 1) {
            w2r[(m - 1) * 64 + n] = bf16_rne(qr);    // Re(Ceff2*w^(t+1))
            w2i[(m - 1) * 64 + n] = bf16_rne(-qi);   // -Im(...)
        }
        const float npr = pr * wr - pi * wi;
        pi = pr * wi + pi * wr;
        pr = npr;
    }
    __syncthreads();

    // k[t] = sum_n Re(Ceff2 * w_n^t)
    float s = 0.0f;
    for (int m = 0; m < 64; ++m) s += lds[n * 68 + m];
    klds[n] = s;
    __syncthreads();

    // TLs[t][j] = (j<=t) ? k[t-j] : 0   (lane = j)
    unsigned short* tl = TLs + h * 4096;
    for (int t = 0; t < 64; ++t) {
        const int d = t - n;
        const float kv = (d >= 0) ? klds[d >= 0 ? d : 0] : 0.0f;
        tl[t * 64 + n] = bf16_rne(kv);
    }
}

// ================= phase A: chunk summaries via MFMA =================
__global__ __launch_bounds__(256) void s4d_phaseA(
    const float* __restrict__ x,
    const unsigned short* __restrict__ W1sr, const unsigned short* __restrict__ W1si,
    ushort2* __restrict__ V)
{
    const int h    = blockIdx.x >> 1;
    const int half = blockIdx.x & 1;
    const int lane = threadIdx.x & 63;
    const int wv   = threadIdx.x >> 6;
    const int colw = half * 128 + wv * 32;   // this wave: 32 (b,c) columns
    const int l15  = lane & 15;
    const int quad = lane >> 4;

    f32x4 accr[2][4], acci[2][4];
    #pragma unroll
    for (int a = 0; a < 2; ++a)
        #pragma unroll
        for (int b = 0; b < 4; ++b) { accr[a][b] = (f32x4)0.0f; acci[a][b] = (f32x4)0.0f; }

    // A-frags: X (bf16), lane l: A[m=l15 -> (b,c)][k = quad*8+jj -> j]
    bf16x8 xa[2][2];
    #pragma unroll
    for (int mt = 0; mt < 2; ++mt) {
        const int bc = colw + mt * 16 + l15;
        const int b  = bc >> 5, c = bc & 31;
        const float* xp = x + ((size_t)(b * H_ + h)) * L_ + c * Q_;
        #pragma unroll
        for (int kk = 0; kk < 2; ++kk) {
            const int j0 = kk * 32 + quad * 8;
            const float4 f0 = *(const float4*)(xp + j0);
            const float4 f1 = *(const float4*)(xp + j0 + 4);
            bf16x8 v;
            v[0] = (short)bf16_rne(f0.x); v[1] = (short)bf16_rne(f0.y);
            v[2] = (short)bf16_rne(f0.z); v[3] = (short)bf16_rne(f0.w);
            v[4] = (short)bf16_rne(f1.x); v[5] = (short)bf16_rne(f1.y);
            v[6] = (short)bf16_rne(f1.z); v[7] = (short)bf16_rne(f1.w);
            xa[mt][kk] = v;
        }
    }

    const unsigned short* w1r = W1sr + h * 4096;
    const unsigned short* w1i = W1si + h * 4096;

    #pragma unroll
    for (int nt = 0; nt < 4; ++nt) {
        const int n = nt * 16 + l15;
        bf16x8 brf[2], bif[2];
        #pragma unroll
        for (int kk = 0; kk < 2; ++kk) {
            const int j0 = kk * 32 + quad * 8;
            brf[kk] = *(const bf16x8*)(w1r + n * 64 + j0);
            bif[kk] = *(const bf16x8*)(w1i + n * 64 + j0);
        }
        #pragma unroll
        for (int mt = 0; mt < 2; ++mt)
            #pragma unroll
            for (int kk = 0; kk < 2; ++kk) {
                accr[mt][nt] = __builtin_amdgcn_mfma_f32_16x16x32_bf16(
                    xa[mt][kk], brf[kk], accr[mt][nt], 0, 0, 0);
                acci[mt][nt] = __builtin_amdgcn_mfma_f32_16x16x32_bf16(
                    xa[mt][kk], bif[kk], acci[mt][nt], 0, 0, 0);
            }
    }

    // store V[(h*256+bc)*64+n] = (bf16 r, bf16 i); lanes 0..15 -> consecutive n
    #pragma unroll
    for (int mt = 0; mt < 2; ++mt)
        #pragma unroll
        for (int nt = 0; nt < 4; ++nt)
            #pragma unroll
            for (int r = 0; r < 4; ++r) {
                const int bc = colw + mt * 16 + quad * 4 + r;
                const int n  = nt * 16 + l15;
                ushort2 o;
                o.x = bf16_rne(accr[mt][nt][r]);
                o.y = bf16_rne(acci[mt][nt][r]);
                V[((size_t)h * COLS_ + bc) * 64 + n] = o;
            }
}

// ================= phase B: scan summaries -> entering states =================
__global__ __launch_bounds__(256) void s4d_phaseB(
    const float2* __restrict__ Earr, ushort2* __restrict__ V)
{
    const int hb = blockIdx.x * 4 + (threadIdx.x >> 6);  // h*8 + b
    const int h = hb >> 3, b = hb & 7;
    const int n = threadIdx.x & 63;

    const float2 E = Earr[h * N_ + n];
    float sr = 0.0f, si = 0.0f;
    ushort2* vp = V + ((size_t)h * COLS_ + b * NC_) * 64 + n;

    for (int c = 0; c < NC_; ++c) {
        const ushort2 vv = vp[c * 64];
        const float vr = bf16_to_f(vv.x);
        const float vi = bf16_to_f(vv.y);
        ushort2 o;                       // state ENTERING chunk c
        o.x = bf16_rne(sr);
        o.y = bf16_rne(si);
        vp[c * 64] = o;
        const float nsr = fmaf(E.x, sr, fmaf(-E.y, si, vr));
        si = fmaf(E.y, sr, fmaf(E.x, si, vi));
        sr = nsr;
    }
}

// ================= phase C: Toeplitz + carry via MFMA, relu =================
__global__ __launch_bounds__(256) void s4d_phaseC(
    const float* __restrict__ x,
    const unsigned short* __restrict__ TLs,
    const unsigned short* __restrict__ W2sr, const unsigned short* __restrict__ W2si,
    const ushort2* __restrict__ V,
    float* __restrict__ out)
{
    const int h    = blockIdx.x >> 1;
    const int half = blockIdx.x & 1;
    const int lane = threadIdx.x & 63;
    const int wv   = threadIdx.x >> 6;
    const int colw = half * 128 + wv * 32;
    const int l15  = lane & 15;
    const int quad = lane >> 4;

    f32x4 acc[2][4];
    #pragma unroll
    for (int a = 0; a < 2; ++a)
        #pragma unroll
        for (int t = 0; t < 4; ++t) acc[a][t] = (f32x4)0.0f;

    bf16x8 xhi[2][2], xlo[2][2], sr8[2][2], si8[2][2];
    #pragma unroll
    for (int mt = 0; mt < 2; ++mt) {
        const int bc = colw + mt * 16 + l15;
        const int b  = bc >> 5, c = bc & 31;
        const float* xp = x + ((size_t)(b * H_ + h)) * L_ + c * Q_;
        const unsigned int* sp =
            (const unsigned int*)(V + ((size_t)h * COLS_ + bc) * 64);
        #pragma unroll
        for (int kk = 0; kk < 2; ++kk) {
            const int j0 = kk * 32 + quad * 8;
            const float4 f0 = *(const float4*)(xp + j0);
            const float4 f1 = *(const float4*)(xp + j0 + 4);
            float f[8] = {f0.x, f0.y, f0.z, f0.w, f1.x, f1.y, f1.z, f1.w};
            bf16x8 hi, lo;
            #pragma unroll
            for (int j = 0; j < 8; ++j) {
                const unsigned short hb = bf16_rne(f[j]);
                hi[j] = (short)hb;
                lo[j] = (short)bf16_rne(f[j] - bf16_to_f(hb));
            }
            xhi[mt][kk] = hi;
            xlo[mt][kk] = lo;
            // S fragments: 8 consecutive n as ushort2 (already bf16 bits)
            bf16x8 fr, fi;
            #pragma unroll
            for (int j = 0; j < 8; ++j) {
                const unsigned int u = sp[j0 + j];
                fr[j] = (short)(u & 0xFFFFu);
                fi[j] = (short)(u >> 16);
            }
            sr8[mt][kk] = fr;
            si8[mt][kk] = fi;
        }
    }

    const unsigned short* tl  = TLs  + h * 4096;
    const unsigned short* w2r = W2sr + h * 4096;
    const unsigned short* w2i = W2si + h * 4096;

    #pragma unroll
    for (int tt = 0; tt < 4; ++tt) {
        const int t = tt * 16 + l15;
        bf16x8 btl[2], bwr[2], bwi[2];
        #pragma unroll
        for (int kk = 0; kk < 2; ++kk) {
            const int j0 = kk * 32 + quad * 8;
            btl[kk] = *(const bf16x8*)(tl  + t * 64 + j0);
            bwr[kk] = *(const bf16x8*)(w2r + t * 64 + j0);
            bwi[kk] = *(const bf16x8*)(w2i + t * 64 + j0);
        }
        #pragma unroll
        for (int mt = 0; mt < 2; ++mt)
            #pragma unroll
            for (int kk = 0; kk < 2; ++kk) {
                acc[mt][tt] = __builtin_amdgcn_mfma_f32_16x16x32_bf16(
                    xhi[mt][kk], btl[kk], acc[mt][tt], 0, 0, 0);
                acc[mt][tt] = __builtin_amdgcn_mfma_f32_16x16x32_bf16(
                    xlo[mt][kk], btl[kk], acc[mt][tt], 0, 0, 0);
                acc[mt][tt] = __builtin_amdgcn_mfma_f32_16x16x32_bf16(
                    sr8[mt][kk], bwr[kk], acc[mt][tt], 0, 0, 0);
                acc[mt][tt] = __builtin_amdgcn_mfma_f32_16x16x32_bf16(
                    si8[mt][kk], bwi[kk], acc[mt][tt], 0, 0, 0);
            }
    }

    // store y, relu; lanes 0..15 -> consecutive t (64B lines)
    #pragma unroll
    for (int mt = 0; mt < 2; ++mt)
        #pragma unroll
        for (int tt = 0; tt < 4; ++tt)
            #pragma unroll
            for (int r = 0; r < 4; ++r) {
                const int bc = colw + mt * 16 + quad * 4 + r;
                const int b  = bc >> 5, c = bc & 31;
                const int t  = tt * 16 + l15;
                out[((size_t)(b * H_ + h)) * L_ + c * Q_ + t] =
                    fmaxf(acc[mt][tt][r], 0.0f);
            }
}

extern "C" void kernel_launch(void* const* d_in, const int* in_sizes, int n_in,
                              void* d_out, int out_size, void* d_ws, size_t ws_size,
                              hipStream_t stream) {
    const float* x      = (const float*)d_in[0];
    const float* A_real = (const float*)d_in[1];
    const float* A_imag = (const float*)d_in[2];
    const float* Bmat   = (const float*)d_in[3];
    const float* Cmat   = (const float*)d_in[4];
    const float* inv_dt = (const float*)d_in[5];
    float* out = (float*)d_out;

    char* ws = (char*)d_ws;
    ushort2*        V    = (ushort2*)(ws + WS_V);
    unsigned short* W1sr = (unsigned short*)(ws + WS_W1R);
    unsigned short* W1si = (unsigned short*)(ws + WS_W1I);
    unsigned short* TLs  = (unsigned short*)(ws + WS_TL);
    unsigned short* W2sr = (unsigned short*)(ws + WS_W2R);
    unsigned short* W2si = (unsigned short*)(ws + WS_W2I);
    float2*         Earr = (float2*)(ws + WS_E);

    s4d_prep<<<dim3(H_), dim3(64), 0, stream>>>(
        A_real, A_imag, Bmat, Cmat, inv_dt, W1sr, W1si, TLs, W2sr, W2si, Earr);
    s4d_phaseA<<<dim3(H_ * 2), dim3(256), 0, stream>>>(x, W1sr, W1si, V);
    s4d_phaseB<<<dim3(512), dim3(256), 0, stream>>>(Earr, V);
    s4d_phaseC<<<dim3(H_ * 2), dim3(256), 0, stream>>>(x, TLs, W2sr, W2si, V, out);
}

// Round 5
// 105.971 us; speedup vs baseline: 1.6341x; 1.1227x over previous
//
#include <hip/hip_runtime.h>

// S4D via chunked MFMA reformulation, fused A+B+C (R4).
//
//  y[c*64+t] = sum_j k[t-j]*x[c*64+j]              (lower-tri Toeplitz, local)
//            + Re( sum_n Ceff2_n w_n^{t+1} S_n[c] ) (carry from prior chunks)
//  S_n[c]    = w^64 * S_n[c-1] + V_n[c-1],  V_n[c] = sum_j w_n^{63-j} x[c*64+j]
//
//  prep  : per h, build bf16 matrices in GLOBAL ws (L2-resident):
//          W1s[n][j]=w^(63-j), TLs[t][j]=k[t-j], W2sr/W2si[t][n]=Re/-Im(Ceff2*w^(t+1))
//  fused : per (h, b-half) block (4 waves, 128 (b,c) cols):
//          - load x frags once (hi/lo bf16 split) -> VGPRs, reused in A and C
//          - phase A: MFMA V = X*W1^T (complex) -> LDS (rows padded to 68
//            words => <=2-way bank aliasing, free)
//          - phase B: in-LDS chunk scan, one (b,n) chain per thread,
//            reads prefetched into regs (no dependent-latency serialization)
//          - phase C: MFMA y = Xhi*TL + Xlo*TL + Sr*W2r + Si*W2i, relu, store
//  Removes vs R3: 67 MB of V global traffic, the latency-bound phaseB
//  kernel, x's second read, 2 launches.
//
//  MFMA layouts (verified by R3 pass): A[m=l&15][k=(l>>4)*8+j];
//  B[k=(l>>4)*8+j][n=l&15]; D[row=(l>>4)*4+r][col=l&15].

#define B_ 8
#define H_ 256
#define N_ 64
#define L_ 2048
#define Q_ 64
#define NC_ 32
#define COLS_ 128       // (b,c) columns per fused block (4 batches x 32 chunks)
#define VSTR_ 68        // LDS V row stride in words (64 + 4 pad; 272B = 17*16)

typedef __attribute__((ext_vector_type(8))) short bf16x8;
typedef __attribute__((ext_vector_type(4))) float f32x4;

// ---- ws layout (bytes): 5 bf16 matrices, 2 MiB each ----
#define WS_W1R  0
#define WS_W1I  (WS_W1R + 2097152)
#define WS_TL   (WS_W1I + 2097152)
#define WS_W2R  (WS_TL  + 2097152)
#define WS_W2I  (WS_W2R + 2097152)

__device__ __forceinline__ unsigned short bf16_rne(float f) {
    unsigned int u = __float_as_uint(f);
    u += 0x7FFF + ((u >> 16) & 1);
    return (unsigned short)(u >> 16);
}
__device__ __forceinline__ float bf16_to_f(unsigned short h) {
    return __uint_as_float(((unsigned int)h) << 16);
}

// ================= prep: per-h parameter matrices (global) =================
__global__ __launch_bounds__(64) void s4d_prep(
    const float* __restrict__ A_real, const float* __restrict__ A_imag,
    const float* __restrict__ Bmat, const float* __restrict__ Cmat,
    const float* __restrict__ inv_dt,
    unsigned short* __restrict__ W1sr, unsigned short* __restrict__ W1si,
    unsigned short* __restrict__ TLs,
    unsigned short* __restrict__ W2sr, unsigned short* __restrict__ W2si)
{
    __shared__ float lds[64 * 68];
    __shared__ float klds[64];

    const int h = blockIdx.x;
    const int n = threadIdx.x;
    const int hn = h * N_ + n;

    const float Ar = -expf(A_real[hn]);     // A = -exp(A_real) - i*A_imag
    const float Ai = -A_imag[hn];
    const float dtv = expf(inv_dt[h]);
    const float dr = dtv * Ar;
    const float di = dtv * Ai;
    const float ew = expf(dr);
    float sdi, cdi;
    sincosf(di, &sdi, &cdi);
    const float wr = ew * cdi;              // w = exp(dt*A)
    const float wi = ew * sdi;
    const float em1r = wr - 1.0f;           // (w-1)/A
    const float em1i = wi;
    const float invden = 1.0f / (Ar * Ar + Ai * Ai);
    const float tr = (em1r * Ar + em1i * Ai) * invden;
    const float ti = (em1i * Ar - em1r * Ai) * invden;
    const float br = Bmat[2 * hn], bi = Bmat[2 * hn + 1];
    const float cr = Cmat[2 * hn], ci = Cmat[2 * hn + 1];
    const float bcr = br * cr - bi * ci;
    const float bci = br * ci + bi * cr;
    const float Cr = 2.0f * (bcr * tr - bci * ti);   // Ceff2 = 2*B*C*(w-1)/A
    const float Ci = 2.0f * (bcr * ti + bci * tr);

    unsigned short* w1r = W1sr + h * 4096;
    unsigned short* w1i = W1si + h * 4096;
    unsigned short* w2r = W2sr + h * 4096;
    unsigned short* w2i = W2si + h * 4096;

    float pr = 1.0f, pi = 0.0f;             // w^m
    for (int m = 0; m <= 64; ++m) {
        const float qr = Cr * pr - Ci * pi; // Re(Ceff2 * w^m)
        const float qi = Cr * pi + Ci * pr;
        if (m < 64) {
            lds[m * 68 + n] = qr;
            w1r[n * 64 + (63 - m)] = bf16_rne(pr);   // W1s[n][j]=w^(63-j)
            w1i[n * 64 + (63 - m)] = bf16_rne(pi);
        }
        if (m >= 1) {
            w2r[(m - 1) * 64 + n] = bf16_rne(qr);    // Re(Ceff2*w^(t+1))
            w2i[(m - 1) * 64 + n] = bf16_rne(-qi);   // -Im(...)
        }
        const float npr = pr * wr - pi * wi;
        pi = pr * wi + pi * wr;
        pr = npr;
    }
    __syncthreads();

    // k[t] = sum_n Re(Ceff2 * w_n^t)
    float s = 0.0f;
    for (int m = 0; m < 64; ++m) s += lds[n * 68 + m];
    klds[n] = s;
    __syncthreads();

    // TLs[t][j] = (j<=t) ? k[t-j] : 0   (lane = j)
    unsigned short* tl = TLs + h * 4096;
    for (int t = 0; t < 64; ++t) {
        const int d = t - n;
        const float kv = (d >= 0) ? klds[d >= 0 ? d : 0] : 0.0f;
        tl[t * 64 + n] = bf16_rne(kv);
    }
}

// ================= fused: V-GEMM -> in-LDS scan -> y-GEMM =================
__global__ __launch_bounds__(256) void s4d_fused(
    const float* __restrict__ x,
    const float* __restrict__ A_real, const float* __restrict__ A_imag,
    const float* __restrict__ inv_dt,
    const unsigned short* __restrict__ W1sr, const unsigned short* __restrict__ W1si,
    const unsigned short* __restrict__ TLs,
    const unsigned short* __restrict__ W2sr, const unsigned short* __restrict__ W2si,
    float* __restrict__ out)
{
    __shared__ unsigned int vlds[COLS_ * VSTR_];   // 34.8 KB: V/S as packed bf16 pair

    const int h     = blockIdx.x >> 1;
    const int bhalf = blockIdx.x & 1;
    const int lane  = threadIdx.x & 63;
    const int wv    = threadIdx.x >> 6;
    const int colw  = wv * 32;                     // this wave's 32 (b,c) cols
    const int l15   = lane & 15;
    const int quad  = lane >> 4;

    // ---- x fragments, loaded ONCE (hi/lo bf16 split), reused in A and C ----
    bf16x8 xhi[2][2], xlo[2][2];
    #pragma unroll
    for (int mt = 0; mt < 2; ++mt) {
        const int bc = colw + mt * 16 + l15;
        const int b  = bhalf * 4 + (bc >> 5);
        const int c  = bc & 31;
        const float* xp = x + ((size_t)(b * H_ + h)) * L_ + c * Q_;
        #pragma unroll
        for (int kk = 0; kk < 2; ++kk) {
            const int j0 = kk * 32 + quad * 8;
            const float4 f0 = *(const float4*)(xp + j0);
            const float4 f1 = *(const float4*)(xp + j0 + 4);
            float f[8] = {f0.x, f0.y, f0.z, f0.w, f1.x, f1.y, f1.z, f1.w};
            bf16x8 hi, lo;
            #pragma unroll
            for (int j = 0; j < 8; ++j) {
                const unsigned short hb = bf16_rne(f[j]);
                hi[j] = (short)hb;
                lo[j] = (short)bf16_rne(f[j] - bf16_to_f(hb));
            }
            xhi[mt][kk] = hi;
            xlo[mt][kk] = lo;
        }
    }

    // ---- per-thread E = w^64 for n = lane (scan coefficient) ----
    float Er, Ei;
    {
        const int hn = h * N_ + lane;
        const float Ar = -expf(A_real[hn]);
        const float Ai = -A_imag[hn];
        const float dtv = expf(inv_dt[h]);
        const float dr = dtv * Ar;
        const float di = dtv * Ai;
        const float e64 = expf(64.0f * dr);
        float s64, c64;
        sincosf(64.0f * di, &s64, &c64);
        Er = e64 * c64;
        Ei = e64 * s64;
    }

    // ---- phase A: V[(b,c)][n] = X * W1^T (complex) -> LDS ----
    {
        const unsigned short* w1r = W1sr + h * 4096;
        const unsigned short* w1i = W1si + h * 4096;

        f32x4 accr[2][4], acci[2][4];
        #pragma unroll
        for (int a = 0; a < 2; ++a)
            #pragma unroll
            for (int b = 0; b < 4; ++b) { accr[a][b] = (f32x4)0.0f; acci[a][b] = (f32x4)0.0f; }

        #pragma unroll
        for (int nt = 0; nt < 4; ++nt) {
            const int n = nt * 16 + l15;
            bf16x8 brf[2], bif[2];
            #pragma unroll
            for (int kk = 0; kk < 2; ++kk) {
                const int j0 = kk * 32 + quad * 8;
                brf[kk] = *(const bf16x8*)(w1r + n * 64 + j0);
                bif[kk] = *(const bf16x8*)(w1i + n * 64 + j0);
            }
            #pragma unroll
            for (int mt = 0; mt < 2; ++mt)
                #pragma unroll
                for (int kk = 0; kk < 2; ++kk) {
                    accr[mt][nt] = __builtin_amdgcn_mfma_f32_16x16x32_bf16(
                        xhi[mt][kk], brf[kk], accr[mt][nt], 0, 0, 0);
                    acci[mt][nt] = __builtin_amdgcn_mfma_f32_16x16x32_bf16(
                        xhi[mt][kk], bif[kk], acci[mt][nt], 0, 0, 0);
                }
        }

        // D layout: row=(quad*4+r) -> bc, col=l15 -> n
        #pragma unroll
        for (int mt = 0; mt < 2; ++mt)
            #pragma unroll
            for (int nt = 0; nt < 4; ++nt)
                #pragma unroll
                for (int r = 0; r < 4; ++r) {
                    const int bc = colw + mt * 16 + quad * 4 + r;
                    const int n  = nt * 16 + l15;
                    const unsigned int pk =
                        (unsigned int)bf16_rne(accr[mt][nt][r]) |
                        ((unsigned int)bf16_rne(acci[mt][nt][r]) << 16);
                    vlds[bc * VSTR_ + n] = pk;
                }
    }
    __syncthreads();

    // ---- phase B: in-LDS scan; thread = (b_local=wv, n=lane) chain ----
    {
        unsigned int* vp = &vlds[(wv * NC_) * VSTR_ + lane];
        unsigned int vv[NC_];
        #pragma unroll
        for (int c = 0; c < NC_; ++c) vv[c] = vp[c * VSTR_];  // prefetch, pipelined

        float sr = 0.0f, si = 0.0f;
        #pragma unroll
        for (int c = 0; c < NC_; ++c) {
            const float vr = bf16_to_f((unsigned short)(vv[c] & 0xFFFFu));
            const float vi = bf16_to_f((unsigned short)(vv[c] >> 16));
            vp[c * VSTR_] = (unsigned int)bf16_rne(sr) |
                            ((unsigned int)bf16_rne(si) << 16);  // state ENTERING c
            const float nsr = fmaf(Er, sr, fmaf(-Ei, si, vr));
            si = fmaf(Ei, sr, fmaf(Er, si, vi));
            sr = nsr;
        }
    }
    __syncthreads();

    // ---- phase C: y = Xhi*TL + Xlo*TL + Sr*W2r + Si*W2i, relu ----
    {
        const unsigned short* tl  = TLs  + h * 4096;
        const unsigned short* w2r = W2sr + h * 4096;
        const unsigned short* w2i = W2si + h * 4096;

        // S fragments from LDS (A-operand layout, same cols as x frags)
        bf16x8 sr8[2][2], si8[2][2];
        #pragma unroll
        for (int mt = 0; mt < 2; ++mt) {
            const int bc = colw + mt * 16 + l15;
            const unsigned int* sp = &vlds[bc * VSTR_];
            #pragma unroll
            for (int kk = 0; kk < 2; ++kk) {
                const int j0 = kk * 32 + quad * 8;
                bf16x8 fr, fi;
                #pragma unroll
                for (int j = 0; j < 8; ++j) {
                    const unsigned int u = sp[j0 + j];
                    fr[j] = (short)(u & 0xFFFFu);
                    fi[j] = (short)(u >> 16);
                }
                sr8[mt][kk] = fr;
                si8[mt][kk] = fi;
            }
        }

        f32x4 acc[2][4];
        #pragma unroll
        for (int a = 0; a < 2; ++a)
            #pragma unroll
            for (int t = 0; t < 4; ++t) acc[a][t] = (f32x4)0.0f;

        #pragma unroll
        for (int tt = 0; tt < 4; ++tt) {
            const int t = tt * 16 + l15;
            bf16x8 btl[2], bwr[2], bwi[2];
            #pragma unroll
            for (int kk = 0; kk < 2; ++kk) {
                const int j0 = kk * 32 + quad * 8;
                btl[kk] = *(const bf16x8*)(tl  + t * 64 + j0);
                bwr[kk] = *(const bf16x8*)(w2r + t * 64 + j0);
                bwi[kk] = *(const bf16x8*)(w2i + t * 64 + j0);
            }
            #pragma unroll
            for (int mt = 0; mt < 2; ++mt)
                #pragma unroll
                for (int kk = 0; kk < 2; ++kk) {
                    acc[mt][tt] = __builtin_amdgcn_mfma_f32_16x16x32_bf16(
                        xhi[mt][kk], btl[kk], acc[mt][tt], 0, 0, 0);
                    acc[mt][tt] = __builtin_amdgcn_mfma_f32_16x16x32_bf16(
                        xlo[mt][kk], btl[kk], acc[mt][tt], 0, 0, 0);
                    acc[mt][tt] = __builtin_amdgcn_mfma_f32_16x16x32_bf16(
                        sr8[mt][kk], bwr[kk], acc[mt][tt], 0, 0, 0);
                    acc[mt][tt] = __builtin_amdgcn_mfma_f32_16x16x32_bf16(
                        si8[mt][kk], bwi[kk], acc[mt][tt], 0, 0, 0);
                }
        }

        // store y with relu; lanes 0..15 -> consecutive t (64B segments)
        #pragma unroll
        for (int mt = 0; mt < 2; ++mt)
            #pragma unroll
            for (int tt = 0; tt < 4; ++tt)
                #pragma unroll
                for (int r = 0; r < 4; ++r) {
                    const int bc = colw + mt * 16 + quad * 4 + r;
                    const int b  = bhalf * 4 + (bc >> 5);
                    const int c  = bc & 31;
                    const int t  = tt * 16 + l15;
                    out[((size_t)(b * H_ + h)) * L_ + c * Q_ + t] =
                        fmaxf(acc[mt][tt][r], 0.0f);
                }
    }
}

extern "C" void kernel_launch(void* const* d_in, const int* in_sizes, int n_in,
                              void* d_out, int out_size, void* d_ws, size_t ws_size,
                              hipStream_t stream) {
    const float* x      = (const float*)d_in[0];
    const float* A_real = (const float*)d_in[1];
    const float* A_imag = (const float*)d_in[2];
    const float* Bmat   = (const float*)d_in[3];
    const float* Cmat   = (const float*)d_in[4];
    const float* inv_dt = (const float*)d_in[5];
    float* out = (float*)d_out;

    char* ws = (char*)d_ws;
    unsigned short* W1sr = (unsigned short*)(ws + WS_W1R);
    unsigned short* W1si = (unsigned short*)(ws + WS_W1I);
    unsigned short* TLs  = (unsigned short*)(ws + WS_TL);
    unsigned short* W2sr = (unsigned short*)(ws + WS_W2R);
    unsigned short* W2si = (unsigned short*)(ws + WS_W2I);

    s4d_prep<<<dim3(H_), dim3(64), 0, stream>>>(
        A_real, A_imag, Bmat, Cmat, inv_dt, W1sr, W1si, TLs, W2sr, W2si);
    s4d_fused<<<dim3(H_ * 2), dim3(256), 0, stream>>>(
        x, A_real, A_imag, inv_dt, W1sr, W1si, TLs, W2sr, W2si, out);
}

// Round 6
// 105.453 us; speedup vs baseline: 1.6421x; 1.0049x over previous
//
#include <hip/hip_runtime.h>

// S4D via chunked MFMA reformulation, fused A+B+C (R5: hw bf16 pack + plane LDS).
//
//  y[c*64+t] = sum_j k[t-j]*x[c*64+j]              (lower-tri Toeplitz, local)
//            + Re( sum_n Ceff2_n w_n^{t+1} S_n[c] ) (carry from prior chunks)
//  S_n[c]    = w^64 * S_n[c-1] + V_n[c-1],  V_n[c] = sum_j w_n^{63-j} x[c*64+j]
//
//  prep : per h, bf16 matrices in global ws (L2-resident).
//  fused: per (h, b-half) block, 4 independent waves x 32 (b,c) cols:
//    A: MFMA V = X*W1^T (complex) -> packed LDS rows (stride 68 words)
//    B: per-thread prefetch -> barrier -> scan -> entering states into
//       r/i ushort PLANES (stride 72, 16B-aligned rows; alias packed region)
//    C: S-frags = plain ds_read_b128 from planes (no unpack ALU);
//       y = Xhi*TL + Xlo*TL + Sr*W2r + Si*W2i, relu, coalesced store.
//  bf16 conversions use v_cvt_pk_bf16_f32 when available (1 instr/pair).

#define B_ 8
#define H_ 256
#define N_ 64
#define L_ 2048
#define Q_ 64
#define NC_ 32
#define COLS_ 128
#define PKSTR_ 68      // packed V row stride (uints)
#define PLSTR_ 72      // plane row stride (ushorts); 144 B rows -> 16B-aligned

typedef __attribute__((ext_vector_type(8))) short bf16x8;
typedef __attribute__((ext_vector_type(4))) float f32x4;

// ---- ws layout (bytes): 5 bf16 matrices, 2 MiB each ----
#define WS_W1R  0
#define WS_W1I  (WS_W1R + 2097152)
#define WS_TL   (WS_W1I + 2097152)
#define WS_W2R  (WS_TL  + 2097152)
#define WS_W2I  (WS_W2R + 2097152)

#if defined(__has_builtin)
#  if __has_builtin(__builtin_amdgcn_cvt_pk_bf16_f32)
#    define HAVE_CVT_PK 1
#  endif
#endif

__device__ __forceinline__ unsigned short bf16_rne(float f) {
    unsigned int u = __float_as_uint(f);
    u += 0x7FFF + ((u >> 16) & 1);
    return (unsigned short)(u >> 16);
}
__device__ __forceinline__ float bf16_to_f(unsigned short h) {
    return __uint_as_float(((unsigned int)h) << 16);
}
// pack two floats to bf16x2 (a -> low, b -> high), RNE
__device__ __forceinline__ unsigned int pack_bf16x2(float a, float b) {
#ifdef HAVE_CVT_PK
    typedef __bf16 bf16v2 __attribute__((ext_vector_type(2)));
    bf16v2 p = __builtin_amdgcn_cvt_pk_bf16_f32(a, b);
    return __builtin_bit_cast(unsigned int, p);
#else
    unsigned int ua = __float_as_uint(a);
    ua += 0x7FFF + ((ua >> 16) & 1);
    unsigned int ub = __float_as_uint(b);
    ub += 0x7FFF + ((ub >> 16) & 1);
    return (ua >> 16) | (ub & 0xFFFF0000u);
#endif
}

// ================= prep: per-h parameter matrices (global) =================
__global__ __launch_bounds__(64) void s4d_prep(
    const float* __restrict__ A_real, const float* __restrict__ A_imag,
    const float* __restrict__ Bmat, const float* __restrict__ Cmat,
    const float* __restrict__ inv_dt,
    unsigned short* __restrict__ W1sr, unsigned short* __restrict__ W1si,
    unsigned short* __restrict__ TLs,
    unsigned short* __restrict__ W2sr, unsigned short* __restrict__ W2si)
{
    __shared__ float lds[64 * 68];
    __shared__ float klds[64];

    const int h = blockIdx.x;
    const int n = threadIdx.x;
    const int hn = h * N_ + n;

    const float Ar = -expf(A_real[hn]);     // A = -exp(A_real) - i*A_imag
    const float Ai = -A_imag[hn];
    const float dtv = expf(inv_dt[h]);
    const float dr = dtv * Ar;
    const float di = dtv * Ai;
    const float ew = expf(dr);
    float sdi, cdi;
    sincosf(di, &sdi, &cdi);
    const float wr = ew * cdi;              // w = exp(dt*A)
    const float wi = ew * sdi;
    const float em1r = wr - 1.0f;           // (w-1)/A
    const float em1i = wi;
    const float invden = 1.0f / (Ar * Ar + Ai * Ai);
    const float tr = (em1r * Ar + em1i * Ai) * invden;
    const float ti = (em1i * Ar - em1r * Ai) * invden;
    const float br = Bmat[2 * hn], bi = Bmat[2 * hn + 1];
    const float cr = Cmat[2 * hn], ci = Cmat[2 * hn + 1];
    const float bcr = br * cr - bi * ci;
    const float bci = br * ci + bi * cr;
    const float Cr = 2.0f * (bcr * tr - bci * ti);   // Ceff2 = 2*B*C*(w-1)/A
    const float Ci = 2.0f * (bcr * ti + bci * tr);

    unsigned short* w1r = W1sr + h * 4096;
    unsigned short* w1i = W1si + h * 4096;
    unsigned short* w2r = W2sr + h * 4096;
    unsigned short* w2i = W2si + h * 4096;

    float pr = 1.0f, pi = 0.0f;             // w^m
    for (int m = 0; m <= 64; ++m) {
        const float qr = Cr * pr - Ci * pi; // Re(Ceff2 * w^m)
        const float qi = Cr * pi + Ci * pr;
        if (m < 64) {
            lds[m * 68 + n] = qr;
            w1r[n * 64 + (63 - m)] = bf16_rne(pr);   // W1s[n][j]=w^(63-j)
            w1i[n * 64 + (63 - m)] = bf16_rne(pi);
        }
        if (m >= 1) {
            w2r[(m - 1) * 64 + n] = bf16_rne(qr);    // Re(Ceff2*w^(t+1))
            w2i[(m - 1) * 64 + n] = bf16_rne(-qi);   // -Im(...)
        }
        const float npr = pr * wr - pi * wi;
        pi = pr * wi + pi * wr;
        pr = npr;
    }
    __syncthreads();

    // k[t] = sum_n Re(Ceff2 * w_n^t)
    float s = 0.0f;
    for (int m = 0; m < 64; ++m) s += lds[n * 68 + m];
    klds[n] = s;
    __syncthreads();

    // TLs[t][j] = (j<=t) ? k[t-j] : 0   (lane = j)
    unsigned short* tl = TLs + h * 4096;
    for (int t = 0; t < 64; ++t) {
        const int d = t - n;
        const float kv = (d >= 0) ? klds[d >= 0 ? d : 0] : 0.0f;
        tl[t * 64 + n] = bf16_rne(kv);
    }
}

// ================= fused: V-GEMM -> in-LDS scan -> y-GEMM =================
__global__ __launch_bounds__(256) void s4d_fused(
    const float* __restrict__ x,
    const float* __restrict__ A_real, const float* __restrict__ A_imag,
    const float* __restrict__ inv_dt,
    const unsigned short* __restrict__ W1sr, const unsigned short* __restrict__ W1si,
    const unsigned short* __restrict__ TLs,
    const unsigned short* __restrict__ W2sr, const unsigned short* __restrict__ W2si,
    float* __restrict__ out)
{
    // packed V (COLS_*68 uints = 34816 B) aliased with state planes
    // (2 * COLS_*72 ushorts = 36864 B); barrier separates the lifetimes.
    __shared__ char smem[COLS_ * PLSTR_ * 2 * 2];
    unsigned int*   vpk = (unsigned int*)smem;
    unsigned short* spr = (unsigned short*)smem;
    unsigned short* spi = (unsigned short*)(smem + COLS_ * PLSTR_ * 2);

    const int h     = blockIdx.x >> 1;
    const int bhalf = blockIdx.x & 1;
    const int lane  = threadIdx.x & 63;
    const int wv    = threadIdx.x >> 6;
    const int colw  = wv * 32;
    const int l15   = lane & 15;
    const int quad  = lane >> 4;

    // ---- x fragments, loaded ONCE (hi/lo bf16 split), reused in A and C ----
    bf16x8 xhi[2][2], xlo[2][2];
    #pragma unroll
    for (int mt = 0; mt < 2; ++mt) {
        const int bc = colw + mt * 16 + l15;
        const int b  = bhalf * 4 + (bc >> 5);
        const int c  = bc & 31;
        const float* xp = x + ((size_t)(b * H_ + h)) * L_ + c * Q_;
        #pragma unroll
        for (int kk = 0; kk < 2; ++kk) {
            const int j0 = kk * 32 + quad * 8;
            const float4 f0 = *(const float4*)(xp + j0);
            const float4 f1 = *(const float4*)(xp + j0 + 4);
            float f[8] = {f0.x, f0.y, f0.z, f0.w, f1.x, f1.y, f1.z, f1.w};
            union { unsigned int u[4]; bf16x8 v; } hi, lo;
            #pragma unroll
            for (int p = 0; p < 4; ++p) {
                const unsigned int hp = pack_bf16x2(f[2 * p], f[2 * p + 1]);
                hi.u[p] = hp;
                const float h0 = __uint_as_float(hp << 16);
                const float h1 = __uint_as_float(hp & 0xFFFF0000u);
                lo.u[p] = pack_bf16x2(f[2 * p] - h0, f[2 * p + 1] - h1);
            }
            xhi[mt][kk] = hi.v;
            xlo[mt][kk] = lo.v;
        }
    }

    // ---- per-thread E = w^64 for n = lane (scan coefficient) ----
    float Er, Ei;
    {
        const int hn = h * N_ + lane;
        const float Ar = -expf(A_real[hn]);
        const float Ai = -A_imag[hn];
        const float dtv = expf(inv_dt[h]);
        const float e64 = expf(64.0f * dtv * Ar);
        float s64, c64;
        sincosf(64.0f * dtv * Ai, &s64, &c64);
        Er = e64 * c64;
        Ei = e64 * s64;
    }

    // ---- phase A: V[(b,c)][n] = X * W1^T (complex) -> packed LDS ----
    {
        const unsigned short* w1r = W1sr + h * 4096;
        const unsigned short* w1i = W1si + h * 4096;

        f32x4 accr[2][4], acci[2][4];
        #pragma unroll
        for (int a = 0; a < 2; ++a)
            #pragma unroll
            for (int b = 0; b < 4; ++b) { accr[a][b] = (f32x4)0.0f; acci[a][b] = (f32x4)0.0f; }

        #pragma unroll
        for (int nt = 0; nt < 4; ++nt) {
            const int n = nt * 16 + l15;
            bf16x8 brf[2], bif[2];
            #pragma unroll
            for (int kk = 0; kk < 2; ++kk) {
                const int j0 = kk * 32 + quad * 8;
                brf[kk] = *(const bf16x8*)(w1r + n * 64 + j0);
                bif[kk] = *(const bf16x8*)(w1i + n * 64 + j0);
            }
            #pragma unroll
            for (int mt = 0; mt < 2; ++mt)
                #pragma unroll
                for (int kk = 0; kk < 2; ++kk) {
                    accr[mt][nt] = __builtin_amdgcn_mfma_f32_16x16x32_bf16(
                        xhi[mt][kk], brf[kk], accr[mt][nt], 0, 0, 0);
                    acci[mt][nt] = __builtin_amdgcn_mfma_f32_16x16x32_bf16(
                        xhi[mt][kk], bif[kk], acci[mt][nt], 0, 0, 0);
                }
        }

        // D layout: row=(quad*4+r) -> bc, col=l15 -> n
        #pragma unroll
        for (int mt = 0; mt < 2; ++mt)
            #pragma unroll
            for (int nt = 0; nt < 4; ++nt)
                #pragma unroll
                for (int r = 0; r < 4; ++r) {
                    const int bc = colw + mt * 16 + quad * 4 + r;
                    const int n  = nt * 16 + l15;
                    vpk[bc * PKSTR_ + n] =
                        pack_bf16x2(accr[mt][nt][r], acci[mt][nt][r]);
                }
    }
    __syncthreads();

    // ---- phase B: prefetch packed V -> barrier -> scan -> state planes ----
    {
        unsigned int vv[NC_];
        const unsigned int* vp = &vpk[(wv * NC_) * PKSTR_ + lane];
        #pragma unroll
        for (int c = 0; c < NC_; ++c) vv[c] = vp[c * PKSTR_];
        __syncthreads();                       // packed lifetime ends

        float sr = 0.0f, si = 0.0f;
        unsigned short* pr = &spr[(wv * NC_) * PLSTR_ + lane];
        unsigned short* pi = &spi[(wv * NC_) * PLSTR_ + lane];
        #pragma unroll
        for (int c = 0; c < NC_; ++c) {
            const float vr = __uint_as_float(vv[c] << 16);
            const float vi = __uint_as_float(vv[c] & 0xFFFF0000u);
            const unsigned int sp2 = pack_bf16x2(sr, si);  // entering state
            pr[c * PLSTR_] = (unsigned short)(sp2 & 0xFFFFu);
            pi[c * PLSTR_] = (unsigned short)(sp2 >> 16);
            const float nsr = fmaf(Er, sr, fmaf(-Ei, si, vr));
            si = fmaf(Ei, sr, fmaf(Er, si, vi));
            sr = nsr;
        }
    }
    __syncthreads();

    // ---- phase C: y = Xhi*TL + Xlo*TL + Sr*W2r + Si*W2i, relu ----
    {
        const unsigned short* tl  = TLs  + h * 4096;
        const unsigned short* w2r = W2sr + h * 4096;
        const unsigned short* w2i = W2si + h * 4096;

        // S fragments: plain b128 reads from planes (A-operand layout)
        bf16x8 sr8[2][2], si8[2][2];
        #pragma unroll
        for (int mt = 0; mt < 2; ++mt) {
            const int bc = colw + mt * 16 + l15;
            #pragma unroll
            for (int kk = 0; kk < 2; ++kk) {
                const int j0 = kk * 32 + quad * 8;
                sr8[mt][kk] = *(const bf16x8*)(&spr[bc * PLSTR_ + j0]);
                si8[mt][kk] = *(const bf16x8*)(&spi[bc * PLSTR_ + j0]);
            }
        }

        f32x4 acc[2][4];
        #pragma unroll
        for (int a = 0; a < 2; ++a)
            #pragma unroll
            for (int t = 0; t < 4; ++t) acc[a][t] = (f32x4)0.0f;

        #pragma unroll
        for (int tt = 0; tt < 4; ++tt) {
            const int t = tt * 16 + l15;
            bf16x8 btl[2], bwr[2], bwi[2];
            #pragma unroll
            for (int kk = 0; kk < 2; ++kk) {
                const int j0 = kk * 32 + quad * 8;
                btl[kk] = *(const bf16x8*)(tl  + t * 64 + j0);
                bwr[kk] = *(const bf16x8*)(w2r + t * 64 + j0);
                bwi[kk] = *(const bf16x8*)(w2i + t * 64 + j0);
            }
            #pragma unroll
            for (int mt = 0; mt < 2; ++mt)
                #pragma unroll
                for (int kk = 0; kk < 2; ++kk) {
                    acc[mt][tt] = __builtin_amdgcn_mfma_f32_16x16x32_bf16(
                        xhi[mt][kk], btl[kk], acc[mt][tt], 0, 0, 0);
                    acc[mt][tt] = __builtin_amdgcn_mfma_f32_16x16x32_bf16(
                        xlo[mt][kk], btl[kk], acc[mt][tt], 0, 0, 0);
                    acc[mt][tt] = __builtin_amdgcn_mfma_f32_16x16x32_bf16(
                        sr8[mt][kk], bwr[kk], acc[mt][tt], 0, 0, 0);
                    acc[mt][tt] = __builtin_amdgcn_mfma_f32_16x16x32_bf16(
                        si8[mt][kk], bwi[kk], acc[mt][tt], 0, 0, 0);
                }
        }

        // store y with relu; lanes 0..15 -> consecutive t (64B segments)
        #pragma unroll
        for (int mt = 0; mt < 2; ++mt)
            #pragma unroll
            for (int tt = 0; tt < 4; ++tt)
                #pragma unroll
                for (int r = 0; r < 4; ++r) {
                    const int bc = colw + mt * 16 + quad * 4 + r;
                    const int b  = bhalf * 4 + (bc >> 5);
                    const int c  = bc & 31;
                    const int t  = tt * 16 + l15;
                    out[((size_t)(b * H_ + h)) * L_ + c * Q_ + t] =
                        fmaxf(acc[mt][tt][r], 0.0f);
                }
    }
}

extern "C" void kernel_launch(void* const* d_in, const int* in_sizes, int n_in,
                              void* d_out, int out_size, void* d_ws, size_t ws_size,
                              hipStream_t stream) {
    const float* x      = (const float*)d_in[0];
    const float* A_real = (const float*)d_in[1];
    const float* A_imag = (const float*)d_in[2];
    const float* Bmat   = (const float*)d_in[3];
    const float* Cmat   = (const float*)d_in[4];
    const float* inv_dt = (const float*)d_in[5];
    float* out = (float*)d_out;

    char* ws = (char*)d_ws;
    unsigned short* W1sr = (unsigned short*)(ws + WS_W1R);
    unsigned short* W1si = (unsigned short*)(ws + WS_W1I);
    unsigned short* TLs  = (unsigned short*)(ws + WS_TL);
    unsigned short* W2sr = (unsigned short*)(ws + WS_W2R);
    unsigned short* W2si = (unsigned short*)(ws + WS_W2I);

    s4d_prep<<<dim3(H_), dim3(64), 0, stream>>>(
        A_real, A_imag, Bmat, Cmat, inv_dt, W1sr, W1si, TLs, W2sr, W2si);
    s4d_fused<<<dim3(H_ * 2), dim3(256), 0, stream>>>(
        x, A_real, A_imag, inv_dt, W1sr, W1si, TLs, W2sr, W2si, out);
}